// Round 11
// baseline (1198.246 us; speedup 1.0000x reference)
//
#include <hip/hip_runtime.h>
#include <hip/hip_bf16.h>

#define NW 256      // word-vec width / GraphConv channels
#define D2 512      // 2*NW == ENC
#define PK 1024     // phi input dim (2*NW + ENC)
#define BM 128      // GEMM row tile
#define BK 64       // GEMM K step
#define DPB 8       // docs per block in k_meanvar
#define SCHUNK 1024 // elements per scan block (phase1/3)

typedef unsigned short u16;
typedef short bf16x8 __attribute__((ext_vector_type(8)));
typedef float f32x4 __attribute__((ext_vector_type(4)));

__device__ __forceinline__ float bf2f(u16 u) {
    union { unsigned u; float f; } v; v.u = ((unsigned)u) << 16; return v.f;
}
__device__ __forceinline__ u16 f2bf(float f) {
    union { float f; unsigned u; } v; v.f = f;
    unsigned u = v.u;
    return (u16)((u + 0x7fffu + ((u >> 16) & 1u)) >> 16);  // RNE
}
// fast tanh: 1 - 2/(1+e^{2x}); exact limits at +-inf, ~1e-6 rel err (<< bf16 step)
__device__ __forceinline__ float tanh_fast(float x) {
    return 1.f - 2.f / (1.f + __expf(2.f * x));
}

// ---- async global->LDS staging of one [128][64] bf16 tile ----
// LDS dest is linear (global_load_lds: wave-uniform base + lane*16).
// Bank-conflict fix is both-sides XOR (rule #21): the global SOURCE slot is
// pre-swizzled (s ^ (row&7)) and the ds_read applies the same XOR.
__device__ __forceinline__ void stage_tile(const u16* __restrict__ base, int row0, int maxrow,
                                           int ldk, int k0, u16* lds, int tid) {
    int w = tid >> 6, l = tid & 63;
#pragma unroll
    for (int i = 0; i < 4; ++i) {
        int loadIdx = i * 256 + w * 64 + l;
        int row = loadIdx >> 3, s = loadIdx & 7;
        int srow = row0 + row; if (srow > maxrow) srow = maxrow;
        int scol = k0 + ((s ^ (row & 7)) << 3);
        const u16* g = base + (size_t)srow * ldk + scol;
        u16* ld = lds + (size_t)(i * 256 + w * 64) * 8;   // wave-uniform
        __builtin_amdgcn_global_load_lds((const __attribute__((address_space(1))) void*)g,
                                         (__attribute__((address_space(3))) void*)ld, 16, 0, 0);
    }
}

// swizzled fragment read: logical (row, kc, g) -> 8 bf16
__device__ __forceinline__ bf16x8 lds_frag(const u16* lds, int row, int kc, int g) {
    int byte = (row << 7) + (kc << 6) + (g << 4);
    byte ^= (row & 7) << 4;
    return *(const bf16x8*)((const char*)lds + byte);
}

// ---------------- fused weight prep (wcat + wglu + wphi + stat zero) ----------------
// wglu chunk c (64 output cols) = 4 sub-blocks of 32 rows:
//   rows [0,32): gate1 cols 0-31 | [32,64): gate2 cols 0-31
//   rows [64,96): gate1 cols 32-63 | [96,128): gate2 cols 32-63
// -> each wave (64 W-rows) holds BOTH gates of the same 32 cols.
__global__ void k_wprep(const float* __restrict__ Wrel, const float* __restrict__ Wroot,
                        const float* __restrict__ W1, const float* __restrict__ W2,
                        const float* __restrict__ Wphi,
                        u16* __restrict__ wcat, u16* __restrict__ wglu,
                        u16* __restrict__ wphib, float* __restrict__ sums,
                        float* __restrict__ sumsq, int K) {
    int i = blockIdx.x * blockDim.x + threadIdx.x;   // 0 .. 1024*512
    if (i < NW * D2) {                               // wcat: [256][512]
        int c = i >> 9, k = i & 511;
        float v = (k < NW) ? Wrel[c * NW + k] : Wroot[c * NW + (k - NW)];
        wcat[i] = f2bf(v);
    }
    if (i < 1024 * 512) {                            // wglu interleaved layout
        int row = i >> 9, k = i & 511;
        int c = row >> 7, j = row & 127;
        int sub = j >> 5, jj = j & 31;
        int half = sub & 1, colgrp = sub >> 1;
        int col = c * 64 + colgrp * 32 + jj;
        float v = half ? W2[(size_t)col * D2 + k] : W1[(size_t)col * D2 + k];
        wglu[i] = f2bf(v);
    }
    if (i < 128 * 1024) {                            // wphib: [128][1024], rows>=K zero
        int r = i >> 10, k = i & 1023;
        wphib[i] = f2bf(r < K ? Wphi[(size_t)r * PK + k] : 0.f);
    }
    if (i < NW) { sums[i] = 0.f; sumsq[i] = 0.f; }
}

// ---------------- embedding gather: X[:,NW:2NW] = word_vec[idx] ----------------
__global__ void k_gather(const int* __restrict__ idx, const float* __restrict__ wv,
                         u16* __restrict__ X, int N) {
    int row = blockIdx.x * 4 + (threadIdx.x >> 6);
    int lane = threadIdx.x & 63;
    if (row < N) {
        int id = idx[row];
        float4 v = *(const float4*)(wv + (size_t)id * NW + lane * 4);
        ushort4 o;
        o.x = f2bf(v.x); o.y = f2bf(v.y); o.z = f2bf(v.z); o.w = f2bf(v.w);
        *(ushort4*)(X + (size_t)row * D2 + NW + lane * 4) = o;
    }
}

// ---------------- CSR build ----------------
__global__ void k_hist(const int* __restrict__ ei, int* __restrict__ deg, int E) {
    int e = blockIdx.x * blockDim.x + threadIdx.x;
    if (e < E) atomicAdd(&deg[ei[E + e]], 1);
}
// ---- 3-phase multi-block exclusive scan ----
__global__ __launch_bounds__(256) void k_scan1(const int* __restrict__ deg,
                                               int* __restrict__ bsum, int N) {
    int b = blockIdx.x, t = threadIdx.x;
    int base = b * SCHUNK;
    int s = 0;
#pragma unroll
    for (int j = 0; j < SCHUNK / 256; ++j) {
        int idx = base + j * 256 + t;
        if (idx < N) s += deg[idx];
    }
    __shared__ int ls[256];
    ls[t] = s; __syncthreads();
    for (int d = 128; d > 0; d >>= 1) {
        if (t < d) ls[t] += ls[t + d];
        __syncthreads();
    }
    if (t == 0) bsum[b] = ls[0];
}
__global__ __launch_bounds__(256) void k_scan2(int* __restrict__ bsum,
                                               int* __restrict__ rowptr, int NB, int N) {
    int t = threadIdx.x;
    int v = (t < NB) ? bsum[t] : 0;
    __shared__ int ls[256];
    ls[t] = v; __syncthreads();
    for (int d = 1; d < 256; d <<= 1) {
        int x = (t >= d) ? ls[t - d] : 0;
        __syncthreads();
        ls[t] += x;
        __syncthreads();
    }
    if (t < NB) bsum[t] = ls[t] - v;          // exclusive block offset
    if (t == 255) rowptr[N] = ls[255];        // grand total
}
__global__ __launch_bounds__(256) void k_scan3(int* __restrict__ deg,
                                               const int* __restrict__ bsum,
                                               int* __restrict__ rowptr, int N) {
    int b = blockIdx.x, t = threadIdx.x;
    int tbase = b * SCHUNK + t * 4;
    int loc[4];
    int s = 0;
#pragma unroll
    for (int j = 0; j < 4; ++j) {
        int idx = tbase + j;
        loc[j] = (idx < N) ? deg[idx] : 0;
        s += loc[j];
    }
    __shared__ int ls[256];
    ls[t] = s; __syncthreads();
    for (int d = 1; d < 256; d <<= 1) {
        int x = (t >= d) ? ls[t - d] : 0;
        __syncthreads();
        ls[t] += x;
        __syncthreads();
    }
    int run = bsum[b] + ls[t] - s;            // exclusive prefix at tbase
#pragma unroll
    for (int j = 0; j < 4; ++j) {
        int idx = tbase + j;
        if (idx < N) { rowptr[idx] = run; run += loc[j]; deg[idx] = 0; }
    }
}
__global__ void k_scatter(const int* __restrict__ ei, const float* __restrict__ ew,
                          const int* __restrict__ rowptr, int* __restrict__ cursor,
                          int* __restrict__ ecols, float* __restrict__ evals, int E) {
    int e = blockIdx.x * blockDim.x + threadIdx.x;
    if (e < E) {
        int d = ei[E + e];
        int p = rowptr[d] + atomicAdd(&cursor[d], 1);
        ecols[p] = ei[e];
        evals[p] = ew[e];
    }
}

// ---------------- SpMM (pull): X[:,0:NW] = aggr ----------------
// 2-edge split: lanes 0-31 even edges, lanes 32-63 odd edges; 8 cols/lane.
__global__ void k_spmm(const int* __restrict__ rowptr, const int* __restrict__ ecols,
                       const float* __restrict__ evals, const float* __restrict__ idxw,
                       u16* __restrict__ X, int N) {
    int n = blockIdx.x * 4 + (threadIdx.x >> 6);
    int l = threadIdx.x & 63;
    if (n >= N) return;
    int half = l >> 5, li = l & 31;
    float a[8];
    bf16x8 xv = *(const bf16x8*)(X + (size_t)n * D2 + NW + li * 8);
    float iw = idxw[0];
#pragma unroll
    for (int j = 0; j < 8; ++j) a[j] = half ? 0.f : iw * bf2f((u16)xv[j]);
    int r0 = rowptr[n], r1 = rowptr[n + 1];
#pragma unroll 4
    for (int e = r0 + half; e < r1; e += 2) {
        int s = ecols[e];
        float w = evals[e];
        bf16x8 v = *(const bf16x8*)(X + (size_t)s * D2 + NW + li * 8);
#pragma unroll
        for (int j = 0; j < 8; ++j) a[j] += w * bf2f((u16)v[j]);
    }
#pragma unroll
    for (int j = 0; j < 8; ++j) a[j] += __shfl_xor(a[j], 32);
    if (half == 0) {
        bf16x8 o;
#pragma unroll
        for (int j = 0; j < 8; ++j) o[j] = (short)f2bf(a[j]);
        *(bf16x8*)(X + (size_t)n * D2 + li * 8) = o;
    }
}

// ---------------- h = [aggr|x] @ Wcat^T + brel, fused BN stats ----------------
// Merged-loop: one block per 128-row panel; it = chunk*8 + kt (16 iterations).
// 2M x 2N wave layout (acc[4][4]); per-chunk epilogue at kt==7 (global stores
// + direct global stat atomics -- LDS stays dedicated to staging).
__global__ __launch_bounds__(256) void k_gemm_h(const u16* __restrict__ A, const u16* __restrict__ W,
                                                const float* __restrict__ brel, u16* __restrict__ H,
                                                float* __restrict__ sums, float* __restrict__ sumsq,
                                                int M) {
    int panel = blockIdx.x;
    __shared__ u16 As[2][BM * BK], Ws[2][BM * BK];
    int tid = threadIdx.x;
    int w = tid >> 6, l = tid & 63, l16 = l & 15, g = l >> 4;
    int wr = w >> 1, wc = w & 1;
    int row0 = panel * BM;
    f32x4 acc[4][4];
#pragma unroll
    for (int m = 0; m < 4; ++m)
#pragma unroll
        for (int n = 0; n < 4; ++n) { f32x4 z = {0.f, 0.f, 0.f, 0.f}; acc[m][n] = z; }

    stage_tile(A, row0, M - 1, D2, 0, As[0], tid);
    stage_tile(W, 0, 127, D2, 0, Ws[0], tid);
    __syncthreads();
    int buf = 0;
    for (int it = 0; it < 16; ++it) {
        int chunk = it >> 3, kt = it & 7;
        if (it < 15) {
            int nxt = it + 1, nchunk = nxt >> 3, nkt = nxt & 7;
            stage_tile(A, row0, M - 1, D2, nkt * BK, As[buf ^ 1], tid);
            stage_tile(W + (size_t)nchunk * 128 * D2, 0, 127, D2, nkt * BK, Ws[buf ^ 1], tid);
        }
#pragma unroll
        for (int kc = 0; kc < 2; ++kc) {
            bf16x8 af[4], bfr[4];
#pragma unroll
            for (int m = 0; m < 4; ++m) af[m] = lds_frag(As[buf], wr * 64 + m * 16 + l16, kc, g);
#pragma unroll
            for (int n = 0; n < 4; ++n) bfr[n] = lds_frag(Ws[buf], wc * 64 + n * 16 + l16, kc, g);
#pragma unroll
            for (int n = 0; n < 4; ++n)
#pragma unroll
                for (int m = 0; m < 4; ++m)
                    acc[m][n] = __builtin_amdgcn_mfma_f32_16x16x32_bf16(af[m], bfr[n], acc[m][n], 0, 0, 0);
        }
        if (kt == 7) {
            int colb = chunk * 128;
#pragma unroll
            for (int n = 0; n < 4; ++n) {
                int col = colb + wc * 64 + n * 16 + l16;
                float bb = brel[col];
                float cs = 0.f, cq = 0.f;
#pragma unroll
                for (int m = 0; m < 4; ++m) {
                    int row = row0 + wr * 64 + m * 16 + g * 4;
#pragma unroll
                    for (int r = 0; r < 4; ++r) {
                        if (row + r < M) {
                            float v = acc[m][n][r] + bb;
                            H[(size_t)(row + r) * NW + col] = f2bf(v);
                            cs += v; cq += v * v;
                        }
                    }
                }
                cs += __shfl_xor(cs, 16); cs += __shfl_xor(cs, 32);
                cq += __shfl_xor(cq, 16); cq += __shfl_xor(cq, 32);
                if (g == 0) { atomicAdd(&sums[col], cs); atomicAdd(&sumsq[col], cq); }
            }
#pragma unroll
            for (int m = 0; m < 4; ++m)
#pragma unroll
                for (int n = 0; n < 4; ++n) { f32x4 z = {0.f, 0.f, 0.f, 0.f}; acc[m][n] = z; }
        }
        __syncthreads();
        buf ^= 1;
    }
}

// ---------------- BN scale/shift precompute ----------------
__global__ void k_bnprep(const float* __restrict__ sums, const float* __restrict__ sumsq,
                         const float* __restrict__ gamma, const float* __restrict__ beta,
                         float* __restrict__ bnab, int N) {
    int c = threadIdx.x;
    float inv = 1.f / (float)N;
    float mu = sums[c] * inv;
    float var = sumsq[c] * inv - mu * mu;
    float rs = rsqrtf(var + 1e-5f);
    float a = rs * gamma[c];
    bnab[c] = a;
    bnab[NW + c] = beta[c] - mu * a;
}

// ---------------- enc1 in place: X[:,0:NW] = tanh(BN(h)) ----------------
__global__ void k_enc1(const u16* __restrict__ H, const float* __restrict__ bnab,
                       u16* __restrict__ X, int N) {
    int row = blockIdx.x * 4 + (threadIdx.x >> 6);
    int lane = threadIdx.x & 63;
    if (row >= N) return;
    int c = lane * 4;
    ushort4 hv = *(const ushort4*)(H + (size_t)row * NW + c);
    ushort4 o;
    o.x = f2bf(tanh_fast(bf2f(hv.x) * bnab[c + 0] + bnab[NW + c + 0]));
    o.y = f2bf(tanh_fast(bf2f(hv.y) * bnab[c + 1] + bnab[NW + c + 1]));
    o.z = f2bf(tanh_fast(bf2f(hv.z) * bnab[c + 2] + bnab[NW + c + 2]));
    o.w = f2bf(tanh_fast(bf2f(hv.w) * bnab[c + 3] + bnab[NW + c + 3]));
    *(ushort4*)(X + (size_t)row * D2 + c) = o;
}

// ---------------- GLU (merged-loop): enc2 = sigmoid(.W1+b1)*tanh(.W2+b2) ----------------
// One block per 128-row panel; it = chunk*8 + kt (64 iterations). 8x fewer
// block instances than the per-chunk grid -> prologue/drain amortized 8x, and
// the A-panel is re-staged from the SAME XCD's L2 (guaranteed residency after
// chunk 0). 2M x 2N wave layout; wglu interleaved so each wave holds gate1
// (n=0,1) and gate2 (n=2,3) of the SAME 32 cols. Per-chunk epilogue at kt==7
// (global stores only, no LDS), then acc resets.
__global__ __launch_bounds__(256) void k_glu(const u16* __restrict__ A, const u16* __restrict__ Wp,
                                             const float* __restrict__ b1, const float* __restrict__ b2,
                                             u16* __restrict__ enc2, int M) {
    int panel = blockIdx.x;
    __shared__ u16 As[2][BM * BK], Ws[2][BM * BK];
    int tid = threadIdx.x;
    int w = tid >> 6, l = tid & 63, l16 = l & 15, g = l >> 4;
    int wr = w >> 1, wc = w & 1;
    int row0 = panel * BM;
    f32x4 acc[4][4];
#pragma unroll
    for (int m = 0; m < 4; ++m)
#pragma unroll
        for (int n = 0; n < 4; ++n) { f32x4 z = {0.f, 0.f, 0.f, 0.f}; acc[m][n] = z; }

    stage_tile(A, row0, M - 1, D2, 0, As[0], tid);
    stage_tile(Wp, 0, 127, D2, 0, Ws[0], tid);
    __syncthreads();
    int buf = 0;
    for (int it = 0; it < 64; ++it) {
        int chunk = it >> 3, kt = it & 7;
        if (it < 63) {
            int nxt = it + 1, nchunk = nxt >> 3, nkt = nxt & 7;
            stage_tile(A, row0, M - 1, D2, nkt * BK, As[buf ^ 1], tid);
            stage_tile(Wp + (size_t)nchunk * 128 * D2, 0, 127, D2, nkt * BK, Ws[buf ^ 1], tid);
        }
#pragma unroll
        for (int kc = 0; kc < 2; ++kc) {
            bf16x8 af[4], bfr[4];
#pragma unroll
            for (int m = 0; m < 4; ++m) af[m] = lds_frag(As[buf], wr * 64 + m * 16 + l16, kc, g);
#pragma unroll
            for (int n = 0; n < 4; ++n) bfr[n] = lds_frag(Ws[buf], wc * 64 + n * 16 + l16, kc, g);
#pragma unroll
            for (int n = 0; n < 4; ++n)
#pragma unroll
                for (int m = 0; m < 4; ++m)
                    acc[m][n] = __builtin_amdgcn_mfma_f32_16x16x32_bf16(af[m], bfr[n], acc[m][n], 0, 0, 0);
        }
        if (kt == 7) {
            int colb = chunk * 64 + wc * 32;
#pragma unroll
            for (int n = 0; n < 2; ++n) {
                int col = colb + n * 16 + l16;
                float f1 = b1[col], f2 = b2[col];
#pragma unroll
                for (int m = 0; m < 4; ++m) {
                    int row = row0 + wr * 64 + m * 16 + g * 4;
#pragma unroll
                    for (int r = 0; r < 4; ++r) {
                        if (row + r < M) {
                            float g1 = acc[m][n][r] + f1;       // gate1
                            float g2 = acc[m][n + 2][r] + f2;   // gate2, same col
                            float sg = 1.f / (1.f + __expf(-g1));
                            enc2[(size_t)(row + r) * D2 + col] = f2bf(sg * tanh_fast(g2));
                        }
                    }
                }
            }
#pragma unroll
            for (int m = 0; m < 4; ++m)
#pragma unroll
                for (int n = 0; n < 4; ++n) { f32x4 z = {0.f, 0.f, 0.f, 0.f}; acc[m][n] = z; }
        }
        __syncthreads();
        buf ^= 1;
    }
}

// ---------------- doc ranges (x_batch sorted) ----------------
__global__ void k_docptr(const int* __restrict__ xb, int* __restrict__ dp, int N, int B) {
    int b = blockIdx.x * blockDim.x + threadIdx.x;
    if (b <= B) {
        int lo = 0, hi = N;
        while (lo < hi) { int mid = (lo + hi) >> 1; if (xb[mid] < b) lo = mid + 1; else hi = mid; }
        dp[b] = lo;
    }
}

// ---------------- pooled = segment_sum(enc2) ----------------
__global__ void k_pool(const u16* __restrict__ enc2, const int* __restrict__ dp,
                       float* __restrict__ pooled, u16* __restrict__ pooledb, int B) {
    int b = blockIdx.x, t = threadIdx.x;   // 256 threads, 2 cols each
    int r0 = dp[b], r1 = dp[b + 1];
    float a0 = 0.f, a1 = 0.f;
    for (int r = r0; r < r1; ++r) {
        a0 += bf2f(enc2[(size_t)r * D2 + t]);
        a1 += bf2f(enc2[(size_t)r * D2 + 256 + t]);
    }
    pooled[(size_t)b * D2 + t] = a0;
    pooled[(size_t)b * D2 + 256 + t] = a1;
    pooledb[(size_t)b * D2 + t] = f2bf(a0);
    pooledb[(size_t)b * D2 + 256 + t] = f2bf(a1);
}

// ---------------- mean / logvar: 8 docs per block (weight traffic /8) ----------------
__global__ __launch_bounds__(128) void k_meanvar(const float* __restrict__ pooled,
                                                 const float* __restrict__ Wm,
                                                 const float* __restrict__ bm,
                                                 const float* __restrict__ Wv,
                                                 const float* __restrict__ bv,
                                                 float* __restrict__ out, int B, int K) {
    __shared__ float sp[DPB][D2];
    int b0 = blockIdx.x * DPB;
    int t = threadIdx.x;   // 128 threads
    for (int i = t; i < DPB * D2; i += 128) {
        int d = i >> 9, c = i & 511;
        int b = b0 + d;
        sp[d][c] = (b < B) ? pooled[(size_t)b * D2 + c] : 0.f;
    }
    __syncthreads();
    if (t < K) {
        float m[DPB], v[DPB];
#pragma unroll
        for (int d = 0; d < DPB; ++d) { m[d] = 0.f; v[d] = 0.f; }
        const float* wm = Wm + (size_t)t * D2;
        const float* wv = Wv + (size_t)t * D2;
        for (int c = 0; c < D2; ++c) {
            float a = wm[c], bb = wv[c];
#pragma unroll
            for (int d = 0; d < DPB; ++d) {
                m[d] += sp[d][c] * a;     // sp broadcast (same addr all lanes)
                v[d] += sp[d][c] * bb;
            }
        }
        float mb = bm[t], vb = bv[t];
#pragma unroll
        for (int d = 0; d < DPB; ++d) {
            int b = b0 + d;
            if (b < B) {
                out[(size_t)b * K + t] = m[d] + mb;
                out[(size_t)B * K + (size_t)b * K + t] = v[d] + vb;
            }
        }
    }
}

// ---------------- phi (tiled GEMM + in-register softmax) ----------------
// A = [X row (512) | pooledb[doc[row]] (512)], W = wphib[128][1024] (rows>=K zero)
__device__ __forceinline__ void stage_phiA(const u16* __restrict__ X, const u16* __restrict__ PB,
                                           const int* __restrict__ xb, int row0, int M,
                                           int k0, u16* lds, int tid) {
    int w = tid >> 6, l = tid & 63;
#pragma unroll
    for (int i = 0; i < 4; ++i) {
        int loadIdx = i * 256 + w * 64 + l;
        int row = loadIdx >> 3, s = loadIdx & 7;
        int srow = row0 + row; if (srow >= M) srow = M - 1;
        int scol = k0 + ((s ^ (row & 7)) << 3);
        const u16* gsrc = (scol < D2) ? X + (size_t)srow * D2 + scol
                                      : PB + (size_t)xb[srow] * D2 + (scol - D2);
        u16* ld = lds + (size_t)(i * 256 + w * 64) * 8;
        __builtin_amdgcn_global_load_lds((const __attribute__((address_space(1))) void*)gsrc,
                                         (__attribute__((address_space(3))) void*)ld, 16, 0, 0);
    }
}

__global__ __launch_bounds__(256) void k_phi(const u16* __restrict__ X, const u16* __restrict__ PB,
                                             const int* __restrict__ xb, const u16* __restrict__ Wp,
                                             const float* __restrict__ bphi, float* __restrict__ out,
                                             int M, int B, int K) {
    __shared__ u16 As[2][BM * BK], Ws[2][BM * BK];
    int tid = threadIdx.x;
    int w = tid >> 6, l = tid & 63, l16 = l & 15, g = l >> 4;
    int row0 = blockIdx.x * BM;
    f32x4 acc[2][8];
#pragma unroll
    for (int m = 0; m < 2; ++m)
#pragma unroll
        for (int n = 0; n < 8; ++n) { f32x4 z = {0.f, 0.f, 0.f, 0.f}; acc[m][n] = z; }

    stage_phiA(X, PB, xb, row0, M, 0, As[0], tid);
    stage_tile(Wp, 0, 127, PK, 0, Ws[0], tid);
    __syncthreads();
    int buf = 0;
    for (int kt = 0; kt < 16; ++kt) {
        if (kt < 15) {
            stage_phiA(X, PB, xb, row0, M, (kt + 1) * BK, As[buf ^ 1], tid);
            stage_tile(Wp, 0, 127, PK, (kt + 1) * BK, Ws[buf ^ 1], tid);
        }
#pragma unroll
        for (int kc = 0; kc < 2; ++kc) {
            bf16x8 a0 = lds_frag(As[buf], w * 32 + l16, kc, g);
            bf16x8 a1 = lds_frag(As[buf], w * 32 + 16 + l16, kc, g);
#pragma unroll
            for (int n = 0; n < 8; ++n) {
                bf16x8 bb = lds_frag(Ws[buf], n * 16 + l16, kc, g);
                acc[0][n] = __builtin_amdgcn_mfma_f32_16x16x32_bf16(a0, bb, acc[0][n], 0, 0, 0);
                acc[1][n] = __builtin_amdgcn_mfma_f32_16x16x32_bf16(a1, bb, acc[1][n], 0, 0, 0);
            }
        }
        __syncthreads();
        buf ^= 1;
    }
    // softmax epilogue: real cols are n=0..6 (7*16=112 >= K=100); n=7 is pad.
    size_t outoff = (size_t)2 * B * K;
#pragma unroll
    for (int m = 0; m < 2; ++m) {
        int rb = row0 + w * 32 + m * 16 + g * 4;
#pragma unroll
        for (int r = 0; r < 4; ++r) {
            int row = rb + r;
            if (row >= M) continue;   // uniform within 16-lane shuffle group
            float v[7];
            float mx = -1e30f;
#pragma unroll
            for (int n = 0; n < 7; ++n) {
                int col = n * 16 + l16;
                float t = (col < K) ? acc[m][n][r] + bphi[col] : -1e30f;
                v[n] = t;
                mx = fmaxf(mx, t);
            }
            mx = fmaxf(mx, __shfl_xor(mx, 1));
            mx = fmaxf(mx, __shfl_xor(mx, 2));
            mx = fmaxf(mx, __shfl_xor(mx, 4));
            mx = fmaxf(mx, __shfl_xor(mx, 8));
            float s = 0.f;
#pragma unroll
            for (int n = 0; n < 7; ++n) {
                int col = n * 16 + l16;
                float e = (col < K) ? __expf(v[n] - mx) : 0.f;
                v[n] = e;
                s += e;
            }
            s += __shfl_xor(s, 1);
            s += __shfl_xor(s, 2);
            s += __shfl_xor(s, 4);
            s += __shfl_xor(s, 8);
            float inv = 1.f / s;
#pragma unroll
            for (int n = 0; n < 7; ++n) {
                int col = n * 16 + l16;
                if (col < K) out[outoff + (size_t)row * K + col] = v[n] * inv;
            }
        }
    }
}

extern "C" void kernel_launch(void* const* d_in, const int* in_sizes, int n_in,
                              void* d_out, int out_size, void* d_ws, size_t ws_size,
                              hipStream_t stream) {
    const int N = in_sizes[0];
    const int E = in_sizes[4];
    const int K = in_sizes[16];
    const int B = (int)(((size_t)out_size - (size_t)N * K) / (2 * (size_t)K));

    const int*   idx_x   = (const int*)d_in[0];
    const float* idx_w   = (const float*)d_in[1];
    const int*   x_batch = (const int*)d_in[2];
    const int*   ei      = (const int*)d_in[3];
    const float* ew      = (const float*)d_in[4];
    const float* word_vec= (const float*)d_in[5];
    const float* Wrel    = (const float*)d_in[6];
    const float* brel    = (const float*)d_in[7];
    const float* Wroot   = (const float*)d_in[8];
    const float* gamma   = (const float*)d_in[9];
    const float* beta    = (const float*)d_in[10];
    const float* W1      = (const float*)d_in[11];
    const float* b1      = (const float*)d_in[12];
    const float* W2      = (const float*)d_in[13];
    const float* b2      = (const float*)d_in[14];
    const float* Wm      = (const float*)d_in[15];
    const float* bm      = (const float*)d_in[16];
    const float* Wv      = (const float*)d_in[17];
    const float* bv      = (const float*)d_in[18];
    const float* Wphi    = (const float*)d_in[19];
    const float* bphi    = (const float*)d_in[20];
    float* out = (float*)d_out;

    // ---- workspace carving (lifetime-aliased; ~214 MB total) ----
    char* p = (char*)d_ws;
    auto take = [&](size_t bytes) -> char* {
        char* r = p;
        p += (bytes + 255) & ~(size_t)255;
        return r;
    };
    // X: [aggr|x] -> (in place) [enc1|x]; persistent across the whole pass.
    u16* X = (u16*)take((size_t)N * D2 * 2);
    // Y: CSR (dead after spmm) -> h in first half (dead after enc1) -> enc2 (glu..pool)
    char* Ybase = take((size_t)N * D2 * 2);
    u16*   hb   = (u16*)Ybase;            // [N][NW] bf16
    u16*   enc2 = (u16*)Ybase;            // [N][D2] bf16
    char* q = Ybase;
    auto takeY = [&](size_t bytes) -> char* {
        char* r = q;
        q += (bytes + 255) & ~(size_t)255;
        return r;
    };
    int*   rowptr = (int*)takeY((size_t)(N + 1) * 4);
    int*   cursor = (int*)takeY((size_t)N * 4);
    int*   ecols  = (int*)takeY((size_t)E * 4);
    float* evals  = (float*)takeY((size_t)E * 4);
    // persistent small buffers
    u16*   wcat    = (u16*)take((size_t)NW * D2 * 2);
    u16*   wglu    = (u16*)take((size_t)1024 * D2 * 2);
    u16*   wphib   = (u16*)take((size_t)128 * PK * 2);
    int*   docptr  = (int*)take((size_t)(B + 1) * 4);
    float* pooled  = (float*)take((size_t)B * D2 * 4);
    u16*   pooledb = (u16*)take((size_t)B * D2 * 2);
    float* sums    = (float*)take(NW * 4);
    float* sumsq   = (float*)take(NW * 4);
    float* bnab    = (float*)take(2 * NW * 4);
    int*   bsum    = (int*)take(256 * 4);

    // Guard: if workspace is too small, launch nothing (clean absmax-fail signal
    // instead of a GPU memory fault).
    if ((size_t)(p - (char*)d_ws) > ws_size) return;

    hipMemsetAsync(cursor, 0, (size_t)N * 4, stream);

    k_wprep<<<(1024 * 512 + 255) / 256, 256, 0, stream>>>(Wrel, Wroot, W1, W2, Wphi,
                                                          wcat, wglu, wphib, sums, sumsq, K);

    k_gather<<<(N + 3) / 4, 256, 0, stream>>>(idx_x, word_vec, X, N);
    k_hist<<<(E + 255) / 256, 256, 0, stream>>>(ei, cursor, E);
    int NB = (N + SCHUNK - 1) / SCHUNK;
    k_scan1<<<NB, 256, 0, stream>>>(cursor, bsum, N);
    k_scan2<<<1, 256, 0, stream>>>(bsum, rowptr, NB, N);
    k_scan3<<<NB, 256, 0, stream>>>(cursor, bsum, rowptr, N);
    k_scatter<<<(E + 255) / 256, 256, 0, stream>>>(ei, ew, rowptr, cursor, ecols, evals, E);
    k_spmm<<<(N + 3) / 4, 256, 0, stream>>>(rowptr, ecols, evals, idx_w, X, N);

    int MT = (N + BM - 1) / BM;
    k_gemm_h<<<MT, 256, 0, stream>>>(X, wcat, brel, hb, sums, sumsq, N);
    k_bnprep<<<1, NW, 0, stream>>>(sums, sumsq, gamma, beta, bnab, N);
    k_enc1<<<(N + 3) / 4, 256, 0, stream>>>(hb, bnab, X, N);

    k_glu<<<MT, 256, 0, stream>>>(X, wglu, b1, b2, enc2, N);

    k_docptr<<<(B + 1 + 255) / 256, 256, 0, stream>>>(x_batch, docptr, N, B);
    k_pool<<<B, 256, 0, stream>>>(enc2, docptr, pooled, pooledb, B);
    k_meanvar<<<(B + DPB - 1) / DPB, 128, 0, stream>>>(pooled, Wm, bm, Wv, bv, out, B, K);
    k_phi<<<MT, 256, 0, stream>>>(X, pooledb, x_batch, wphib, bphi, out, N, B, K);
}

// Round 12
// 764.240 us; speedup vs baseline: 1.5679x; 1.5679x over previous
//
#include <hip/hip_runtime.h>
#include <hip/hip_bf16.h>

#define NW 256      // word-vec width / GraphConv channels
#define D2 512      // 2*NW == ENC
#define PK 1024     // phi input dim (2*NW + ENC)
#define BM 128      // GEMM row tile
#define BK 64       // GEMM K step
#define DPB 8       // docs per block in k_meanvar
#define SCHUNK 1024 // elements per scan block (phase1/3)

typedef unsigned short u16;
typedef short bf16x8 __attribute__((ext_vector_type(8)));
typedef float f32x4 __attribute__((ext_vector_type(4)));

__device__ __forceinline__ float bf2f(u16 u) {
    union { unsigned u; float f; } v; v.u = ((unsigned)u) << 16; return v.f;
}
__device__ __forceinline__ u16 f2bf(float f) {
    union { float f; unsigned u; } v; v.f = f;
    unsigned u = v.u;
    return (u16)((u + 0x7fffu + ((u >> 16) & 1u)) >> 16);  // RNE
}
// fast tanh: 1 - 2/(1+e^{2x}); exact limits at +-inf, ~1e-6 rel err (<< bf16 step)
__device__ __forceinline__ float tanh_fast(float x) {
    return 1.f - 2.f / (1.f + __expf(2.f * x));
}

// ---- async global->LDS staging of one [128][64] bf16 tile (BK=64 path) ----
// LDS dest is linear (global_load_lds: wave-uniform base + lane*16).
// Bank-conflict fix is both-sides XOR (rule #21): the global SOURCE slot is
// pre-swizzled (s ^ (row&7)) and the ds_read applies the same XOR.
__device__ __forceinline__ void stage_tile(const u16* __restrict__ base, int row0, int maxrow,
                                           int ldk, int k0, u16* lds, int tid) {
    int w = tid >> 6, l = tid & 63;
#pragma unroll
    for (int i = 0; i < 4; ++i) {
        int loadIdx = i * 256 + w * 64 + l;
        int row = loadIdx >> 3, s = loadIdx & 7;
        int srow = row0 + row; if (srow > maxrow) srow = maxrow;
        int scol = k0 + ((s ^ (row & 7)) << 3);
        const u16* g = base + (size_t)srow * ldk + scol;
        u16* ld = lds + (size_t)(i * 256 + w * 64) * 8;   // wave-uniform
        __builtin_amdgcn_global_load_lds((const __attribute__((address_space(1))) void*)g,
                                         (__attribute__((address_space(3))) void*)ld, 16, 0, 0);
    }
}

// swizzled fragment read (BK=64): logical (row, kc, g) -> 8 bf16
__device__ __forceinline__ bf16x8 lds_frag(const u16* lds, int row, int kc, int g) {
    int byte = (row << 7) + (kc << 6) + (g << 4);
    byte ^= (row & 7) << 4;
    return *(const bf16x8*)((const char*)lds + byte);
}

// ---- BK=32 staging: [128][32] bf16 tile = 64 lines x 128B (row-pair/line) ----
// line = row>>1, slot(8 x 16B) = (row&1)*4 + g; source pre-swizzled slot^(line&3)
// (involution within the line) -> ds_read max 2-way conflict (free, m136).
__device__ __forceinline__ void stage32(const u16* __restrict__ base, int row0, int maxrow,
                                        int ldk, int k0, u16* lds, int tid) {
    int w = tid >> 6, l = tid & 63;
#pragma unroll
    for (int i = 0; i < 2; ++i) {
        int loadIdx = i * 256 + w * 64 + l;       // 0..511
        int line = loadIdx >> 3, sp = loadIdx & 7;
        int slot = sp ^ (line & 3);
        int row = line * 2 + (slot >> 2);
        int g = slot & 3;
        int srow = row0 + row; if (srow > maxrow) srow = maxrow;
        int scol = k0 + g * 8;
        const u16* gp = base + (size_t)srow * ldk + scol;
        u16* ld = lds + (size_t)(i * 256 + w * 64) * 8;   // wave-uniform
        __builtin_amdgcn_global_load_lds((const __attribute__((address_space(1))) void*)gp,
                                         (__attribute__((address_space(3))) void*)ld, 16, 0, 0);
    }
}
// fragment read (BK=32): logical (row, g) -> 8 bf16
__device__ __forceinline__ bf16x8 lds_frag32(const u16* lds, int row, int g) {
    int line = row >> 1;
    int slot = ((row & 1) << 2) + g;
    int byte = line * 128 + ((slot ^ (line & 3)) << 4);
    return *(const bf16x8*)((const char*)lds + byte);
}

// ---------------- fused weight prep (wcat + wglu + wphi + stat zero) ----------------
// wglu chunk c (64 output cols) = 4 sub-blocks of 32 rows:
//   rows [0,32): gate1 cols 0-31 | [32,64): gate2 cols 0-31
//   rows [64,96): gate1 cols 32-63 | [96,128): gate2 cols 32-63
// -> each wave (64 W-rows) holds BOTH gates of the same 32 cols.
__global__ void k_wprep(const float* __restrict__ Wrel, const float* __restrict__ Wroot,
                        const float* __restrict__ W1, const float* __restrict__ W2,
                        const float* __restrict__ Wphi,
                        u16* __restrict__ wcat, u16* __restrict__ wglu,
                        u16* __restrict__ wphib, float* __restrict__ sums,
                        float* __restrict__ sumsq, int K) {
    int i = blockIdx.x * blockDim.x + threadIdx.x;   // 0 .. 1024*512
    if (i < NW * D2) {                               // wcat: [256][512]
        int c = i >> 9, k = i & 511;
        float v = (k < NW) ? Wrel[c * NW + k] : Wroot[c * NW + (k - NW)];
        wcat[i] = f2bf(v);
    }
    if (i < 1024 * 512) {                            // wglu interleaved layout
        int row = i >> 9, k = i & 511;
        int c = row >> 7, j = row & 127;
        int sub = j >> 5, jj = j & 31;
        int half = sub & 1, colgrp = sub >> 1;
        int col = c * 64 + colgrp * 32 + jj;
        float v = half ? W2[(size_t)col * D2 + k] : W1[(size_t)col * D2 + k];
        wglu[i] = f2bf(v);
    }
    if (i < 128 * 1024) {                            // wphib: [128][1024], rows>=K zero
        int r = i >> 10, k = i & 1023;
        wphib[i] = f2bf(r < K ? Wphi[(size_t)r * PK + k] : 0.f);
    }
    if (i < NW) { sums[i] = 0.f; sumsq[i] = 0.f; }
}

// ---------------- embedding gather: X[:,NW:2NW] = word_vec[idx] ----------------
__global__ void k_gather(const int* __restrict__ idx, const float* __restrict__ wv,
                         u16* __restrict__ X, int N) {
    int row = blockIdx.x * 4 + (threadIdx.x >> 6);
    int lane = threadIdx.x & 63;
    if (row < N) {
        int id = idx[row];
        float4 v = *(const float4*)(wv + (size_t)id * NW + lane * 4);
        ushort4 o;
        o.x = f2bf(v.x); o.y = f2bf(v.y); o.z = f2bf(v.z); o.w = f2bf(v.w);
        *(ushort4*)(X + (size_t)row * D2 + NW + lane * 4) = o;
    }
}

// ---------------- CSR build ----------------
__global__ void k_hist(const int* __restrict__ ei, int* __restrict__ deg, int E) {
    int e = blockIdx.x * blockDim.x + threadIdx.x;
    if (e < E) atomicAdd(&deg[ei[E + e]], 1);
}
// ---- 3-phase multi-block exclusive scan ----
__global__ __launch_bounds__(256) void k_scan1(const int* __restrict__ deg,
                                               int* __restrict__ bsum, int N) {
    int b = blockIdx.x, t = threadIdx.x;
    int base = b * SCHUNK;
    int s = 0;
#pragma unroll
    for (int j = 0; j < SCHUNK / 256; ++j) {
        int idx = base + j * 256 + t;
        if (idx < N) s += deg[idx];
    }
    __shared__ int ls[256];
    ls[t] = s; __syncthreads();
    for (int d = 128; d > 0; d >>= 1) {
        if (t < d) ls[t] += ls[t + d];
        __syncthreads();
    }
    if (t == 0) bsum[b] = ls[0];
}
__global__ __launch_bounds__(256) void k_scan2(int* __restrict__ bsum,
                                               int* __restrict__ rowptr, int NB, int N) {
    int t = threadIdx.x;
    int v = (t < NB) ? bsum[t] : 0;
    __shared__ int ls[256];
    ls[t] = v; __syncthreads();
    for (int d = 1; d < 256; d <<= 1) {
        int x = (t >= d) ? ls[t - d] : 0;
        __syncthreads();
        ls[t] += x;
        __syncthreads();
    }
    if (t < NB) bsum[t] = ls[t] - v;          // exclusive block offset
    if (t == 255) rowptr[N] = ls[255];        // grand total
}
__global__ __launch_bounds__(256) void k_scan3(int* __restrict__ deg,
                                               const int* __restrict__ bsum,
                                               int* __restrict__ rowptr, int N) {
    int b = blockIdx.x, t = threadIdx.x;
    int tbase = b * SCHUNK + t * 4;
    int loc[4];
    int s = 0;
#pragma unroll
    for (int j = 0; j < 4; ++j) {
        int idx = tbase + j;
        loc[j] = (idx < N) ? deg[idx] : 0;
        s += loc[j];
    }
    __shared__ int ls[256];
    ls[t] = s; __syncthreads();
    for (int d = 1; d < 256; d <<= 1) {
        int x = (t >= d) ? ls[t - d] : 0;
        __syncthreads();
        ls[t] += x;
        __syncthreads();
    }
    int run = bsum[b] + ls[t] - s;            // exclusive prefix at tbase
#pragma unroll
    for (int j = 0; j < 4; ++j) {
        int idx = tbase + j;
        if (idx < N) { rowptr[idx] = run; run += loc[j]; deg[idx] = 0; }
    }
}
__global__ void k_scatter(const int* __restrict__ ei, const float* __restrict__ ew,
                          const int* __restrict__ rowptr, int* __restrict__ cursor,
                          int* __restrict__ ecols, float* __restrict__ evals, int E) {
    int e = blockIdx.x * blockDim.x + threadIdx.x;
    if (e < E) {
        int d = ei[E + e];
        int p = rowptr[d] + atomicAdd(&cursor[d], 1);
        ecols[p] = ei[e];
        evals[p] = ew[e];
    }
}

// ---------------- SpMM (pull): X[:,0:NW] = aggr ----------------
// 2-edge split: lanes 0-31 even edges, lanes 32-63 odd edges; 8 cols/lane.
__global__ void k_spmm(const int* __restrict__ rowptr, const int* __restrict__ ecols,
                       const float* __restrict__ evals, const float* __restrict__ idxw,
                       u16* __restrict__ X, int N) {
    int n = blockIdx.x * 4 + (threadIdx.x >> 6);
    int l = threadIdx.x & 63;
    if (n >= N) return;
    int half = l >> 5, li = l & 31;
    float a[8];
    bf16x8 xv = *(const bf16x8*)(X + (size_t)n * D2 + NW + li * 8);
    float iw = idxw[0];
#pragma unroll
    for (int j = 0; j < 8; ++j) a[j] = half ? 0.f : iw * bf2f((u16)xv[j]);
    int r0 = rowptr[n], r1 = rowptr[n + 1];
#pragma unroll 4
    for (int e = r0 + half; e < r1; e += 2) {
        int s = ecols[e];
        float w = evals[e];
        bf16x8 v = *(const bf16x8*)(X + (size_t)s * D2 + NW + li * 8);
#pragma unroll
        for (int j = 0; j < 8; ++j) a[j] += w * bf2f((u16)v[j]);
    }
#pragma unroll
    for (int j = 0; j < 8; ++j) a[j] += __shfl_xor(a[j], 32);
    if (half == 0) {
        bf16x8 o;
#pragma unroll
        for (int j = 0; j < 8; ++j) o[j] = (short)f2bf(a[j]);
        *(bf16x8*)(X + (size_t)n * D2 + li * 8) = o;
    }
}

// ---------------- h = [aggr|x] @ Wcat^T + brel (tiled), fused BN stats ----------------
// 2M x 2N wave layout; XCD-locality remap: chunk fast, panel slow per XCD.
__global__ __launch_bounds__(256) void k_gemm_h(const u16* __restrict__ A, const u16* __restrict__ W,
                                                const float* __restrict__ brel, u16* __restrict__ H,
                                                float* __restrict__ sums, float* __restrict__ sumsq,
                                                int M, int MT) {
    int b = blockIdx.x;
    int xcd = b & 7, j = b >> 3;
    int chunk = j & 1;
    int panel = (j >> 1) * 8 + xcd;
    if (panel >= MT) return;
    __shared__ u16 As[2][BM * BK], Ws[2][BM * BK];
    int tid = threadIdx.x;
    int w = tid >> 6, l = tid & 63, l16 = l & 15, g = l >> 4;
    int wr = w >> 1, wc = w & 1;
    int row0 = panel * BM;
    const u16* wbase = W + (size_t)chunk * 128 * D2;
    f32x4 acc[4][4];
#pragma unroll
    for (int m = 0; m < 4; ++m)
#pragma unroll
        for (int n = 0; n < 4; ++n) { f32x4 z = {0.f, 0.f, 0.f, 0.f}; acc[m][n] = z; }

    stage_tile(A, row0, M - 1, D2, 0, As[0], tid);
    stage_tile(wbase, 0, 127, D2, 0, Ws[0], tid);
    __syncthreads();
    int buf = 0;
    for (int kt = 0; kt < 8; ++kt) {
        if (kt < 7) {
            stage_tile(A, row0, M - 1, D2, (kt + 1) * BK, As[buf ^ 1], tid);
            stage_tile(wbase, 0, 127, D2, (kt + 1) * BK, Ws[buf ^ 1], tid);
        }
#pragma unroll
        for (int kc = 0; kc < 2; ++kc) {
            bf16x8 af[4], bfr[4];
#pragma unroll
            for (int m = 0; m < 4; ++m) af[m] = lds_frag(As[buf], wr * 64 + m * 16 + l16, kc, g);
#pragma unroll
            for (int n = 0; n < 4; ++n) bfr[n] = lds_frag(Ws[buf], wc * 64 + n * 16 + l16, kc, g);
#pragma unroll
            for (int n = 0; n < 4; ++n)
#pragma unroll
                for (int m = 0; m < 4; ++m)
                    acc[m][n] = __builtin_amdgcn_mfma_f32_16x16x32_bf16(af[m], bfr[n], acc[m][n], 0, 0, 0);
        }
        __syncthreads();
        buf ^= 1;
    }
    // epilogue: bias + store bf16 + per-column stats (reuse staging LDS)
    float* ssum = (float*)As[0];
    float* ssq  = ssum + 128;
    if (tid < 128) { ssum[tid] = 0.f; ssq[tid] = 0.f; }
    __syncthreads();
    int colb = chunk * 128;
#pragma unroll
    for (int n = 0; n < 4; ++n) {
        int lcol = wc * 64 + n * 16 + l16;
        int col = colb + lcol;
        float bb = brel[col];
        float cs = 0.f, cq = 0.f;
#pragma unroll
        for (int m = 0; m < 4; ++m) {
            int row = row0 + wr * 64 + m * 16 + g * 4;
#pragma unroll
            for (int r = 0; r < 4; ++r) {
                if (row + r < M) {
                    float v = acc[m][n][r] + bb;
                    H[(size_t)(row + r) * NW + col] = f2bf(v);
                    cs += v; cq += v * v;
                }
            }
        }
        cs += __shfl_xor(cs, 16); cs += __shfl_xor(cs, 32);
        cq += __shfl_xor(cq, 16); cq += __shfl_xor(cq, 32);
        if (g == 0) { atomicAdd(&ssum[lcol], cs); atomicAdd(&ssq[lcol], cq); }
    }
    __syncthreads();
    if (tid < 128) {
        atomicAdd(&sums[colb + tid], ssum[tid]);
        atomicAdd(&sumsq[colb + tid], ssq[tid]);
    }
}

// ---------------- BN scale/shift precompute ----------------
__global__ void k_bnprep(const float* __restrict__ sums, const float* __restrict__ sumsq,
                         const float* __restrict__ gamma, const float* __restrict__ beta,
                         float* __restrict__ bnab, int N) {
    int c = threadIdx.x;
    float inv = 1.f / (float)N;
    float mu = sums[c] * inv;
    float var = sumsq[c] * inv - mu * mu;
    float rs = rsqrtf(var + 1e-5f);
    float a = rs * gamma[c];
    bnab[c] = a;
    bnab[NW + c] = beta[c] - mu * a;
}

// ---------------- enc1 in place: X[:,0:NW] = tanh(BN(h)) ----------------
__global__ void k_enc1(const u16* __restrict__ H, const float* __restrict__ bnab,
                       u16* __restrict__ X, int N) {
    int row = blockIdx.x * 4 + (threadIdx.x >> 6);
    int lane = threadIdx.x & 63;
    if (row >= N) return;
    int c = lane * 4;
    ushort4 hv = *(const ushort4*)(H + (size_t)row * NW + c);
    ushort4 o;
    o.x = f2bf(tanh_fast(bf2f(hv.x) * bnab[c + 0] + bnab[NW + c + 0]));
    o.y = f2bf(tanh_fast(bf2f(hv.y) * bnab[c + 1] + bnab[NW + c + 1]));
    o.z = f2bf(tanh_fast(bf2f(hv.z) * bnab[c + 2] + bnab[NW + c + 2]));
    o.w = f2bf(tanh_fast(bf2f(hv.w) * bnab[c + 3] + bnab[NW + c + 3]));
    *(ushort4*)(X + (size_t)row * D2 + c) = o;
}

// ---------------- GLU (tiled, fused, BK=32): sigmoid(.W1+b1)*tanh(.W2+b2) ----------------
// Same grid/remap/wave-layout as the proven BK=64 version; BK=32 halves LDS to
// 32KB -> 5 blocks/CU (vs 2), raising cross-block TLP that hides the 2-phase
// barrier drain (m114/m233). 16 K-steps of 32 == same MFMA K-slab order as
// 8 steps x (2x32) -> bit-identical accumulation. wglu interleaved: each wave
// holds gate1 (n=0,1) and gate2 (n=2,3) of the SAME 32 cols.
__global__ __launch_bounds__(256) void k_glu(const u16* __restrict__ A, const u16* __restrict__ Wp,
                                             const float* __restrict__ b1, const float* __restrict__ b2,
                                             u16* __restrict__ enc2, int M, int MT) {
    int b = blockIdx.x;
    int xcd = b & 7, j = b >> 3;
    int chunk = j & 7;
    int panel = (j >> 3) * 8 + xcd;
    if (panel >= MT) return;
    __shared__ u16 As[2][BM * 32], Ws[2][BM * 32];
    int tid = threadIdx.x;
    int w = tid >> 6, l = tid & 63, l16 = l & 15, g = l >> 4;
    int wr = w >> 1, wc = w & 1;
    int row0 = panel * BM;
    const u16* wbase = Wp + (size_t)chunk * 128 * D2;
    f32x4 acc[4][4];
#pragma unroll
    for (int m = 0; m < 4; ++m)
#pragma unroll
        for (int n = 0; n < 4; ++n) { f32x4 z = {0.f, 0.f, 0.f, 0.f}; acc[m][n] = z; }

    stage32(A, row0, M - 1, D2, 0, As[0], tid);
    stage32(wbase, 0, 127, D2, 0, Ws[0], tid);
    __syncthreads();
    int buf = 0;
    for (int kt = 0; kt < 16; ++kt) {
        if (kt < 15) {
            stage32(A, row0, M - 1, D2, (kt + 1) * 32, As[buf ^ 1], tid);
            stage32(wbase, 0, 127, D2, (kt + 1) * 32, Ws[buf ^ 1], tid);
        }
        {
            bf16x8 af[4], bfr[4];
#pragma unroll
            for (int m = 0; m < 4; ++m) af[m] = lds_frag32(As[buf], wr * 64 + m * 16 + l16, g);
#pragma unroll
            for (int n = 0; n < 4; ++n) bfr[n] = lds_frag32(Ws[buf], wc * 64 + n * 16 + l16, g);
#pragma unroll
            for (int n = 0; n < 4; ++n)
#pragma unroll
                for (int m = 0; m < 4; ++m)
                    acc[m][n] = __builtin_amdgcn_mfma_f32_16x16x32_bf16(af[m], bfr[n], acc[m][n], 0, 0, 0);
        }
        __syncthreads();
        buf ^= 1;
    }
    int colb = chunk * 64 + wc * 32;
#pragma unroll
    for (int n = 0; n < 2; ++n) {
        int col = colb + n * 16 + l16;
        float f1 = b1[col], f2 = b2[col];
#pragma unroll
        for (int m = 0; m < 4; ++m) {
            int row = row0 + wr * 64 + m * 16 + g * 4;
#pragma unroll
            for (int r = 0; r < 4; ++r) {
                if (row + r < M) {
                    float g1 = acc[m][n][r] + f1;       // gate1
                    float g2 = acc[m][n + 2][r] + f2;   // gate2, same col
                    float sg = 1.f / (1.f + __expf(-g1));
                    enc2[(size_t)(row + r) * D2 + col] = f2bf(sg * tanh_fast(g2));
                }
            }
        }
    }
}

// ---------------- doc ranges (x_batch sorted) ----------------
__global__ void k_docptr(const int* __restrict__ xb, int* __restrict__ dp, int N, int B) {
    int b = blockIdx.x * blockDim.x + threadIdx.x;
    if (b <= B) {
        int lo = 0, hi = N;
        while (lo < hi) { int mid = (lo + hi) >> 1; if (xb[mid] < b) lo = mid + 1; else hi = mid; }
        dp[b] = lo;
    }
}

// ---------------- pooled = segment_sum(enc2) ----------------
__global__ void k_pool(const u16* __restrict__ enc2, const int* __restrict__ dp,
                       float* __restrict__ pooled, u16* __restrict__ pooledb, int B) {
    int b = blockIdx.x, t = threadIdx.x;   // 256 threads, 2 cols each
    int r0 = dp[b], r1 = dp[b + 1];
    float a0 = 0.f, a1 = 0.f;
    for (int r = r0; r < r1; ++r) {
        a0 += bf2f(enc2[(size_t)r * D2 + t]);
        a1 += bf2f(enc2[(size_t)r * D2 + 256 + t]);
    }
    pooled[(size_t)b * D2 + t] = a0;
    pooled[(size_t)b * D2 + 256 + t] = a1;
    pooledb[(size_t)b * D2 + t] = f2bf(a0);
    pooledb[(size_t)b * D2 + 256 + t] = f2bf(a1);
}

// ---------------- mean / logvar: 8 docs per block (weight traffic /8) ----------------
__global__ __launch_bounds__(128) void k_meanvar(const float* __restrict__ pooled,
                                                 const float* __restrict__ Wm,
                                                 const float* __restrict__ bm,
                                                 const float* __restrict__ Wv,
                                                 const float* __restrict__ bv,
                                                 float* __restrict__ out, int B, int K) {
    __shared__ float sp[DPB][D2];
    int b0 = blockIdx.x * DPB;
    int t = threadIdx.x;   // 128 threads
    for (int i = t; i < DPB * D2; i += 128) {
        int d = i >> 9, c = i & 511;
        int b = b0 + d;
        sp[d][c] = (b < B) ? pooled[(size_t)b * D2 + c] : 0.f;
    }
    __syncthreads();
    if (t < K) {
        float m[DPB], v[DPB];
#pragma unroll
        for (int d = 0; d < DPB; ++d) { m[d] = 0.f; v[d] = 0.f; }
        const float* wm = Wm + (size_t)t * D2;
        const float* wv = Wv + (size_t)t * D2;
        for (int c = 0; c < D2; ++c) {
            float a = wm[c], bb = wv[c];
#pragma unroll
            for (int d = 0; d < DPB; ++d) {
                m[d] += sp[d][c] * a;     // sp broadcast (same addr all lanes)
                v[d] += sp[d][c] * bb;
            }
        }
        float mb = bm[t], vb = bv[t];
#pragma unroll
        for (int d = 0; d < DPB; ++d) {
            int b = b0 + d;
            if (b < B) {
                out[(size_t)b * K + t] = m[d] + mb;
                out[(size_t)B * K + (size_t)b * K + t] = v[d] + vb;
            }
        }
    }
}

// ---------------- phi (tiled GEMM + in-register softmax) ----------------
// A = [X row (512) | pooledb[doc[row]] (512)], W = wphib[128][1024] (rows>=K zero)
__device__ __forceinline__ void stage_phiA(const u16* __restrict__ X, const u16* __restrict__ PB,
                                           const int* __restrict__ xb, int row0, int M,
                                           int k0, u16* lds, int tid) {
    int w = tid >> 6, l = tid & 63;
#pragma unroll
    for (int i = 0; i < 4; ++i) {
        int loadIdx = i * 256 + w * 64 + l;
        int row = loadIdx >> 3, s = loadIdx & 7;
        int srow = row0 + row; if (srow >= M) srow = M - 1;
        int scol = k0 + ((s ^ (row & 7)) << 3);
        const u16* gsrc = (scol < D2) ? X + (size_t)srow * D2 + scol
                                      : PB + (size_t)xb[srow] * D2 + (scol - D2);
        u16* ld = lds + (size_t)(i * 256 + w * 64) * 8;
        __builtin_amdgcn_global_load_lds((const __attribute__((address_space(1))) void*)gsrc,
                                         (__attribute__((address_space(3))) void*)ld, 16, 0, 0);
    }
}

__global__ __launch_bounds__(256) void k_phi(const u16* __restrict__ X, const u16* __restrict__ PB,
                                             const int* __restrict__ xb, const u16* __restrict__ Wp,
                                             const float* __restrict__ bphi, float* __restrict__ out,
                                             int M, int B, int K) {
    __shared__ u16 As[2][BM * BK], Ws[2][BM * BK];
    int tid = threadIdx.x;
    int w = tid >> 6, l = tid & 63, l16 = l & 15, g = l >> 4;
    int row0 = blockIdx.x * BM;
    f32x4 acc[2][8];
#pragma unroll
    for (int m = 0; m < 2; ++m)
#pragma unroll
        for (int n = 0; n < 8; ++n) { f32x4 z = {0.f, 0.f, 0.f, 0.f}; acc[m][n] = z; }

    stage_phiA(X, PB, xb, row0, M, 0, As[0], tid);
    stage_tile(Wp, 0, 127, PK, 0, Ws[0], tid);
    __syncthreads();
    int buf = 0;
    for (int kt = 0; kt < 16; ++kt) {
        if (kt < 15) {
            stage_phiA(X, PB, xb, row0, M, (kt + 1) * BK, As[buf ^ 1], tid);
            stage_tile(Wp, 0, 127, PK, (kt + 1) * BK, Ws[buf ^ 1], tid);
        }
#pragma unroll
        for (int kc = 0; kc < 2; ++kc) {
            bf16x8 a0 = lds_frag(As[buf], w * 32 + l16, kc, g);
            bf16x8 a1 = lds_frag(As[buf], w * 32 + 16 + l16, kc, g);
#pragma unroll
            for (int n = 0; n < 8; ++n) {
                bf16x8 bb = lds_frag(Ws[buf], n * 16 + l16, kc, g);
                acc[0][n] = __builtin_amdgcn_mfma_f32_16x16x32_bf16(a0, bb, acc[0][n], 0, 0, 0);
                acc[1][n] = __builtin_amdgcn_mfma_f32_16x16x32_bf16(a1, bb, acc[1][n], 0, 0, 0);
            }
        }
        __syncthreads();
        buf ^= 1;
    }
    // softmax epilogue: real cols are n=0..6 (7*16=112 >= K=100); n=7 is pad.
    size_t outoff = (size_t)2 * B * K;
#pragma unroll
    for (int m = 0; m < 2; ++m) {
        int rb = row0 + w * 32 + m * 16 + g * 4;
#pragma unroll
        for (int r = 0; r < 4; ++r) {
            int row = rb + r;
            if (row >= M) continue;   // uniform within 16-lane shuffle group
            float v[7];
            float mx = -1e30f;
#pragma unroll
            for (int n = 0; n < 7; ++n) {
                int col = n * 16 + l16;
                float t = (col < K) ? acc[m][n][r] + bphi[col] : -1e30f;
                v[n] = t;
                mx = fmaxf(mx, t);
            }
            mx = fmaxf(mx, __shfl_xor(mx, 1));
            mx = fmaxf(mx, __shfl_xor(mx, 2));
            mx = fmaxf(mx, __shfl_xor(mx, 4));
            mx = fmaxf(mx, __shfl_xor(mx, 8));
            float s = 0.f;
#pragma unroll
            for (int n = 0; n < 7; ++n) {
                int col = n * 16 + l16;
                float e = (col < K) ? __expf(v[n] - mx) : 0.f;
                v[n] = e;
                s += e;
            }
            s += __shfl_xor(s, 1);
            s += __shfl_xor(s, 2);
            s += __shfl_xor(s, 4);
            s += __shfl_xor(s, 8);
            float inv = 1.f / s;
#pragma unroll
            for (int n = 0; n < 7; ++n) {
                int col = n * 16 + l16;
                if (col < K) out[outoff + (size_t)row * K + col] = v[n] * inv;
            }
        }
    }
}

extern "C" void kernel_launch(void* const* d_in, const int* in_sizes, int n_in,
                              void* d_out, int out_size, void* d_ws, size_t ws_size,
                              hipStream_t stream) {
    const int N = in_sizes[0];
    const int E = in_sizes[4];
    const int K = in_sizes[16];
    const int B = (int)(((size_t)out_size - (size_t)N * K) / (2 * (size_t)K));

    const int*   idx_x   = (const int*)d_in[0];
    const float* idx_w   = (const float*)d_in[1];
    const int*   x_batch = (const int*)d_in[2];
    const int*   ei      = (const int*)d_in[3];
    const float* ew      = (const float*)d_in[4];
    const float* word_vec= (const float*)d_in[5];
    const float* Wrel    = (const float*)d_in[6];
    const float* brel    = (const float*)d_in[7];
    const float* Wroot   = (const float*)d_in[8];
    const float* gamma   = (const float*)d_in[9];
    const float* beta    = (const float*)d_in[10];
    const float* W1      = (const float*)d_in[11];
    const float* b1      = (const float*)d_in[12];
    const float* W2      = (const float*)d_in[13];
    const float* b2      = (const float*)d_in[14];
    const float* Wm      = (const float*)d_in[15];
    const float* bm      = (const float*)d_in[16];
    const float* Wv      = (const float*)d_in[17];
    const float* bv      = (const float*)d_in[18];
    const float* Wphi    = (const float*)d_in[19];
    const float* bphi    = (const float*)d_in[20];
    float* out = (float*)d_out;

    // ---- workspace carving (lifetime-aliased; ~214 MB total) ----
    char* p = (char*)d_ws;
    auto take = [&](size_t bytes) -> char* {
        char* r = p;
        p += (bytes + 255) & ~(size_t)255;
        return r;
    };
    // X: [aggr|x] -> (in place) [enc1|x]; persistent across the whole pass.
    u16* X = (u16*)take((size_t)N * D2 * 2);
    // Y: CSR (dead after spmm) -> h in first half (dead after enc1) -> enc2 (glu..pool)
    char* Ybase = take((size_t)N * D2 * 2);
    u16*   hb   = (u16*)Ybase;            // [N][NW] bf16
    u16*   enc2 = (u16*)Ybase;            // [N][D2] bf16
    char* q = Ybase;
    auto takeY = [&](size_t bytes) -> char* {
        char* r = q;
        q += (bytes + 255) & ~(size_t)255;
        return r;
    };
    int*   rowptr = (int*)takeY((size_t)(N + 1) * 4);
    int*   cursor = (int*)takeY((size_t)N * 4);
    int*   ecols  = (int*)takeY((size_t)E * 4);
    float* evals  = (float*)takeY((size_t)E * 4);
    // persistent small buffers
    u16*   wcat    = (u16*)take((size_t)NW * D2 * 2);
    u16*   wglu    = (u16*)take((size_t)1024 * D2 * 2);
    u16*   wphib   = (u16*)take((size_t)128 * PK * 2);
    int*   docptr  = (int*)take((size_t)(B + 1) * 4);
    float* pooled  = (float*)take((size_t)B * D2 * 4);
    u16*   pooledb = (u16*)take((size_t)B * D2 * 2);
    float* sums    = (float*)take(NW * 4);
    float* sumsq   = (float*)take(NW * 4);
    float* bnab    = (float*)take(2 * NW * 4);
    int*   bsum    = (int*)take(256 * 4);

    // Guard: if workspace is too small, launch nothing (clean absmax-fail signal
    // instead of a GPU memory fault).
    if ((size_t)(p - (char*)d_ws) > ws_size) return;

    hipMemsetAsync(cursor, 0, (size_t)N * 4, stream);

    k_wprep<<<(1024 * 512 + 255) / 256, 256, 0, stream>>>(Wrel, Wroot, W1, W2, Wphi,
                                                          wcat, wglu, wphib, sums, sumsq, K);

    k_gather<<<(N + 3) / 4, 256, 0, stream>>>(idx_x, word_vec, X, N);
    k_hist<<<(E + 255) / 256, 256, 0, stream>>>(ei, cursor, E);
    int NB = (N + SCHUNK - 1) / SCHUNK;
    k_scan1<<<NB, 256, 0, stream>>>(cursor, bsum, N);
    k_scan2<<<1, 256, 0, stream>>>(bsum, rowptr, NB, N);
    k_scan3<<<NB, 256, 0, stream>>>(cursor, bsum, rowptr, N);
    k_scatter<<<(E + 255) / 256, 256, 0, stream>>>(ei, ew, rowptr, cursor, ecols, evals, E);
    k_spmm<<<(N + 3) / 4, 256, 0, stream>>>(rowptr, ecols, evals, idx_w, X, N);

    int MT = (N + BM - 1) / BM;
    int P8 = (MT + 7) / 8;            // panels rounded up to groups of 8
    k_gemm_h<<<P8 * 8 * 2, 256, 0, stream>>>(X, wcat, brel, hb, sums, sumsq, N, MT);
    k_bnprep<<<1, NW, 0, stream>>>(sums, sumsq, gamma, beta, bnab, N);
    k_enc1<<<(N + 3) / 4, 256, 0, stream>>>(hb, bnab, X, N);

    k_glu<<<P8 * 8 * 8, 256, 0, stream>>>(X, wglu, b1, b2, enc2, N, MT);

    k_docptr<<<(B + 1 + 255) / 256, 256, 0, stream>>>(x_batch, docptr, N, B);
    k_pool<<<B, 256, 0, stream>>>(enc2, docptr, pooled, pooledb, B);
    k_meanvar<<<(B + DPB - 1) / DPB, 128, 0, stream>>>(pooled, Wm, bm, Wv, bv, out, B, K);
    k_phi<<<MT, 256, 0, stream>>>(X, pooledb, x_batch, wphib, bphi, out, N, B, K);
}